// Round 6
// baseline (329.753 us; speedup 1.0000x reference)
//
#include <hip/hip_runtime.h>

// ---------------------------------------------------------------------------
// AGNN: h = relu(x@W1^T+b1); 4x [ h = relu(agnn(h)) ]; out = h@W2^T+b2
// N=100000, E=1600000, IN=128, HID=OUT=64, float32 in/out.
// Between layers: xn = h/(||h||+eps) stored FP16 (128 B/row) + nrm f32.
//   p = exp2( dot(xn_i * log2e, xn_j) );  out_i = sum p * nrm_j * xn_j / sum p
// Round 6: PERSISTENT agnn + node-level software pipeline.
//   Model (r2-r5 post-mortems): wave lifetime ~15K cyc for a deg-16 node ->
//   ~1900 cyc per 2-edge iter = intra-iter col->row dependent chain (~600cy)
//   + 3-deep node prologue (perm->ptr->xn), with only 3.8 waves/SIMD to
//   cover. Fix = 2x waves + kill the prologue chain:
//   - 2048 blocks (8/CU resident), __launch_bounds__(256,8) (VGPR<=64),
//     grid-stride over degree-sorted slots.
//   - meta int4 (nid,p0,p1,_) from the sort kernel; meta[k+1] prefetched at
//     node-k top, row[k+1] prefetched before node-k epilogue.
//   - inner loop: round-3 contiguous-half split + 1-pair lookahead,
//     DPP reduces (round 5).
// gemm1/gemm2 (512 thr, prefetch), rowptr scan, 1024-seg sort kept.
// ---------------------------------------------------------------------------

typedef _Float16 h2 __attribute__((ext_vector_type(2)));

union U4H { uint4 u; h2 h[4]; };
union U2H { uint2 u; h2 h[2]; };
union UHI { unsigned u; h2 h; };
union UF  { unsigned u; float f; int i; };

#define DEV_INLINE __device__ __forceinline__

DEV_INLINE h2 mkh2(float a, float b) {
    h2 r; r.x = (_Float16)a; r.y = (_Float16)b; return r;
}

// x + dpp_perm(x): 0xB1 quad_perm xor1, 0x4E quad_perm xor2,
// 0x141 row_half_mirror (i^7), 0x140 row_mirror (i^15).
template <int CTRL>
DEV_INLINE float dpp_addf(float x) {
    UF a, b;
    a.f = x;
    b.i = __builtin_amdgcn_update_dpp(0, a.i, CTRL, 0xF, 0xF, true);
    return x + b.f;
}

// ptr[i] = lower_bound(row, i). Thread e covers i in (row[e-1], row[e]].
__global__ __launch_bounds__(256) void build_rowptr_scan(const int* __restrict__ row,
                                                         int* __restrict__ ptr,
                                                         int N, int E) {
    int e = blockIdx.x * blockDim.x + threadIdx.x;
    if (e >= E) return;
    const int r1 = row[e];
    const int r0 = (e == 0) ? -1 : row[e - 1];
    for (int i = r0 + 1; i <= r1; ++i) ptr[i] = e;
    if (e == E - 1) {
        for (int i = r1 + 1; i <= N; ++i) ptr[i] = E;
    }
}

// Segment-local counting sort by degree; emits meta[pos] = (nid, p0, p1, 0).
#define PSEG 1024
__global__ __launch_bounds__(1024) void build_perm_seg(const int* __restrict__ ptr,
                                                       int4* __restrict__ meta,
                                                       int N) {
    __shared__ int hist[256];
    __shared__ int tmp[256];
    const int t    = threadIdx.x;
    const int base = blockIdx.x * PSEG;
    const int end  = (base + PSEG < N) ? base + PSEG : N;
    const int cnt  = end - base;

    if (t < 256) hist[t] = 0;
    __syncthreads();

    int d = -1, p0v = 0, p1v = 0;
    if (t < cnt) {
        p0v = ptr[base + t];
        p1v = ptr[base + t + 1];
        d = p1v - p0v;
        if (d > 255) d = 255;
        atomicAdd(&hist[d], 1);
    }
    __syncthreads();

    int h0 = (t < 256) ? hist[t] : 0;
    int* src = hist; int* dst = tmp;
    for (int off = 1; off < 256; off <<= 1) {
        if (t < 256) dst[t] = src[t] + (t >= off ? src[t - off] : 0);
        __syncthreads();
        int* tt = src; src = dst; dst = tt;
    }
    if (t < 256) src[t] -= h0;
    __syncthreads();

    if (t < cnt) {
        int pos = base + atomicAdd(&src[d], 1);
        meta[pos] = make_int4(base + t, p0v, p1v, 0);
    }
}

// r = relu(x[i,:128]@W1^T + b1); xn[i]=f16(r/(||r||+eps)); nrm[i]=||r||+eps
// 512 threads, tile 128 nodes x 64 outs, thread = 4 nodes x 4 outs.
__global__ __launch_bounds__(512) void gemm1_relu(const float* __restrict__ x,
                                                  const float* __restrict__ W1,
                                                  const float* __restrict__ b1,
                                                  unsigned short* __restrict__ xn,
                                                  float* __restrict__ nrm,
                                                  int N) {
    __shared__ __align__(16) float Wt[32 * 64];    // 8 KiB
    __shared__ __align__(16) float xT[32 * 128];   // 16 KiB
    const int tid  = threadIdx.x;
    const int tx   = tid & 15;
    const int ty   = tid >> 4;
    const int base = blockIdx.x * 128;

    const float4* W4  = (const float4*)W1;
    const float4* x4p = (const float4*)x;

    const int wO  = tid & 63;
    const int wK4 = tid >> 6;
    const int mA  = tid & 127;
    const int kA  = tid >> 7;
    const int mB  = mA;
    const int kB  = kA + 4;
    const int nodeA = base + mA;

    float4 wv, xa_, xb_;
    wv = W4[wO * 32 + wK4];
    xa_ = make_float4(0.f, 0.f, 0.f, 0.f);
    xb_ = xa_;
    if (nodeA < N) {
        xa_ = x4p[(size_t)nodeA * 32 + kA];
        xb_ = x4p[(size_t)nodeA * 32 + kB];
    }

    float4 b4 = ((const float4*)b1)[tx];
    float4 acc[4];
    acc[0] = b4; acc[1] = b4; acc[2] = b4; acc[3] = b4;

    for (int c = 0; c < 4; ++c) {
        Wt[(4 * wK4 + 0) * 64 + wO] = wv.x;
        Wt[(4 * wK4 + 1) * 64 + wO] = wv.y;
        Wt[(4 * wK4 + 2) * 64 + wO] = wv.z;
        Wt[(4 * wK4 + 3) * 64 + wO] = wv.w;
        xT[(4 * kA + 0) * 128 + mA] = xa_.x;
        xT[(4 * kA + 1) * 128 + mA] = xa_.y;
        xT[(4 * kA + 2) * 128 + mA] = xa_.z;
        xT[(4 * kA + 3) * 128 + mA] = xa_.w;
        xT[(4 * kB + 0) * 128 + mB] = xb_.x;
        xT[(4 * kB + 1) * 128 + mB] = xb_.y;
        xT[(4 * kB + 2) * 128 + mB] = xb_.z;
        xT[(4 * kB + 3) * 128 + mB] = xb_.w;
        __syncthreads();

        if (c < 3) {
            const int ko = (c + 1) * 8;
            wv = W4[wO * 32 + ko + wK4];
            if (nodeA < N) {
                xa_ = x4p[(size_t)nodeA * 32 + ko + kA];
                xb_ = x4p[(size_t)nodeA * 32 + ko + kB];
            }
        }

#pragma unroll 4
        for (int k = 0; k < 32; ++k) {
            const float4 w4 = *(const float4*)&Wt[k * 64 + 4 * tx];
            const float4 xv = *(const float4*)&xT[k * 128 + 4 * ty];
            acc[0].x = fmaf(xv.x, w4.x, acc[0].x);
            acc[0].y = fmaf(xv.x, w4.y, acc[0].y);
            acc[0].z = fmaf(xv.x, w4.z, acc[0].z);
            acc[0].w = fmaf(xv.x, w4.w, acc[0].w);
            acc[1].x = fmaf(xv.y, w4.x, acc[1].x);
            acc[1].y = fmaf(xv.y, w4.y, acc[1].y);
            acc[1].z = fmaf(xv.y, w4.z, acc[1].z);
            acc[1].w = fmaf(xv.y, w4.w, acc[1].w);
            acc[2].x = fmaf(xv.z, w4.x, acc[2].x);
            acc[2].y = fmaf(xv.z, w4.y, acc[2].y);
            acc[2].z = fmaf(xv.z, w4.z, acc[2].z);
            acc[2].w = fmaf(xv.z, w4.w, acc[2].w);
            acc[3].x = fmaf(xv.w, w4.x, acc[3].x);
            acc[3].y = fmaf(xv.w, w4.y, acc[3].y);
            acc[3].z = fmaf(xv.w, w4.z, acc[3].z);
            acc[3].w = fmaf(xv.w, w4.w, acc[3].w);
        }
        if (c < 3) __syncthreads();
    }

#pragma unroll
    for (int mm = 0; mm < 4; ++mm) {
        float4 r = acc[mm];
        r.x = fmaxf(r.x, 0.f); r.y = fmaxf(r.y, 0.f);
        r.z = fmaxf(r.z, 0.f); r.w = fmaxf(r.w, 0.f);
        float s = fmaf(r.x, r.x, fmaf(r.y, r.y, fmaf(r.z, r.z, r.w * r.w)));
        s = dpp_addf<0xB1>(s);
        s = dpp_addf<0x4E>(s);
        s = dpp_addf<0x141>(s);
        s = dpp_addf<0x140>(s);
        const float nn  = sqrtf(s) + 1e-12f;
        const float inv = 1.f / nn;
        int node = base + 4 * ty + mm;
        if (node < N) {
            U2H pk;
            pk.h[0] = mkh2(r.x * inv, r.y * inv);
            pk.h[1] = mkh2(r.z * inv, r.w * inv);
            *(uint2*)&xn[(size_t)node * 64 + 4 * tx] = pk.u;
            if (tx == mm) nrm[node] = nn;
        }
    }
}

// PERSISTENT agnn. 4 nodes/wave (16 lanes), 2 edge-groups x 8 lanes with
// contiguous half-split + 1-pair lookahead; grid-stride over sorted slots;
// meta/row prefetched one node ahead.
__global__ __launch_bounds__(256, 8) void agnn_layer(const uint4* __restrict__ xn4,
                                                     const float* __restrict__ nrm,
                                                     const int4* __restrict__ meta,
                                                     const int* __restrict__ col,
                                                     uint4* __restrict__ xo4,
                                                     float* __restrict__ nrmo,
                                                     int N, int stride) {
    const int tid  = threadIdx.x;
    const int lane = tid & 63;
    const int g    = (lane >> 3) & 1;   // edge group within 16-lane quarter
    const int sub  = lane & 7;          // 16B chunk of the 128B row
    int slot = blockIdx.x * 16 + (tid >> 4);
    if (slot >= N) return;

    int4 m0 = meta[slot];                               // first prologue
    uint4 hraw = xn4[(unsigned)m0.x * 8u + sub];        // (exposed once)

    for (;;) {
        const int snext = slot + stride;
        const int msl   = (snext < N) ? snext : slot;
        const int4 m1   = meta[msl];                    // prefetch next meta

        const int i  = m0.x;
        const int p0 = m0.y, p1 = m0.z;

        U4H hi_;
        hi_.u = hraw;
        {
            const _Float16 L2E = (_Float16)1.4426950408889634f;
            h2 l2 = {L2E, L2E};
#pragma unroll
            for (int c = 0; c < 4; ++c) hi_.h[c] *= l2;
        }

        const int mid = p0 + ((p1 - p0 + 1) >> 1);
        int       t   = g ? mid : p0;
        const int e_  = g ? p1  : mid;

        float den = 0.f;
        U4H acc;
        acc.h[0] = mkh2(0.f, 0.f); acc.h[1] = mkh2(0.f, 0.f);
        acc.h[2] = mkh2(0.f, 0.f); acc.h[3] = mkh2(0.f, 0.f);

#define EDGE_BODY(VU, NRMJ)                                                  \
    {                                                                        \
        U4H xa; xa.u = (VU);                                                 \
        float sa = __builtin_amdgcn_fdot2(hi_.h[0], xa.h[0], 0.f, false);    \
        sa = __builtin_amdgcn_fdot2(hi_.h[1], xa.h[1], sa, false);           \
        float sb = __builtin_amdgcn_fdot2(hi_.h[2], xa.h[2], 0.f, false);    \
        sb = __builtin_amdgcn_fdot2(hi_.h[3], xa.h[3], sb, false);           \
        float s = sa + sb;                                                   \
        s = dpp_addf<0xB1>(s);                                               \
        s = dpp_addf<0x4E>(s);                                               \
        s = dpp_addf<0x141>(s);                                              \
        const float p = exp2f(s);                                            \
        den += p;                                                            \
        const _Float16 wh = (_Float16)(p * (NRMJ));                          \
        h2 w2 = {wh, wh};                                                    \
        acc.h[0] += w2 * xa.h[0];                                            \
        acc.h[1] += w2 * xa.h[1];                                            \
        acc.h[2] += w2 * xa.h[2];                                            \
        acc.h[3] += w2 * xa.h[3];                                            \
    }

        {
            const int n_ = e_ - t;
            int j0 = 0, j1 = 0, j2 = 0, j3 = 0;
            uint4 v0 = make_uint4(0u, 0u, 0u, 0u), v1 = v0;
            float n0 = 0.f, n1 = 0.f;
            if (n_ > 0) j0 = col[t];
            if (n_ > 1) j1 = col[t + 1];
            if (n_ > 0) { v0 = xn4[(unsigned)j0 * 8u + sub]; n0 = nrm[j0]; }
            if (n_ > 1) { v1 = xn4[(unsigned)j1 * 8u + sub]; n1 = nrm[j1]; }
            if (n_ > 2) j2 = col[t + 2];
            if (n_ > 3) j3 = col[t + 3];

            while (t + 5 < e_) {
                const uint4 v2 = xn4[(unsigned)j2 * 8u + sub];
                const float m2 = nrm[j2];
                const uint4 v3 = xn4[(unsigned)j3 * 8u + sub];
                const float m3 = nrm[j3];
                const int j4 = col[t + 4];
                const int j5 = col[t + 5];
                EDGE_BODY(v0, n0)
                EDGE_BODY(v1, n1)
                v0 = v2; n0 = m2; v1 = v3; n1 = m3;
                j2 = j4; j3 = j5;
                t += 2;
            }
            const int rem = e_ - t;   // 0..5
            if (rem > 2) {
                const uint4 v2 = xn4[(unsigned)j2 * 8u + sub];
                const float m2 = nrm[j2];
                uint4 v3 = make_uint4(0u, 0u, 0u, 0u);
                float m3 = 0.f;
                if (rem > 3) { v3 = xn4[(unsigned)j3 * 8u + sub]; m3 = nrm[j3]; }
                int j4 = 0;
                if (rem > 4) j4 = col[t + 4];
                EDGE_BODY(v0, n0)
                EDGE_BODY(v1, n1)
                EDGE_BODY(v2, m2)
                if (rem > 3) EDGE_BODY(v3, m3)
                if (rem > 4) {
                    const uint4 v4 = xn4[(unsigned)j4 * 8u + sub];
                    const float m4 = nrm[j4];
                    EDGE_BODY(v4, m4)
                }
            } else {
                if (rem > 0) EDGE_BODY(v0, n0)
                if (rem > 1) EDGE_BODY(v1, n1)
            }
        }
#undef EDGE_BODY

        // prefetch next node's row (m1 arrived during the edge loop);
        // overlaps the epilogue below + next node's col chain.
        hraw = xn4[(unsigned)m1.x * 8u + sub];

        // merge groups: den group-uniform -> row_mirror; acc exact xor8
        den = dpp_addf<0x140>(den);
#pragma unroll
        for (int c = 0; c < 4; ++c) {
            UHI a; a.h = acc.h[c];
            UHI b; b.u = (unsigned)__shfl_xor((int)a.u, 8, 64);
            acc.h[c] = a.h + b.h;
        }

        const float id = 1.f / fmaxf(den, 1e-12f);
        float o[8];
#pragma unroll
        for (int c = 0; c < 4; ++c) {
            o[2 * c]     = fmaxf((float)acc.h[c].x * id, 0.f);
            o[2 * c + 1] = fmaxf((float)acc.h[c].y * id, 0.f);
        }

        float s2 = 0.f;
#pragma unroll
        for (int c = 0; c < 8; ++c) s2 = fmaf(o[c], o[c], s2);
        s2 = dpp_addf<0xB1>(s2);
        s2 = dpp_addf<0x4E>(s2);
        s2 = dpp_addf<0x141>(s2);
        const float nn  = sqrtf(s2) + 1e-12f;
        const float inv = 1.f / nn;

        if (g == 0) {
            U4H ov;
            ov.h[0] = mkh2(o[0] * inv, o[1] * inv);
            ov.h[1] = mkh2(o[2] * inv, o[3] * inv);
            ov.h[2] = mkh2(o[4] * inv, o[5] * inv);
            ov.h[3] = mkh2(o[6] * inv, o[7] * inv);
            xo4[(unsigned)i * 8u + sub] = ov.u;
            if (sub == 0) nrmo[i] = nn;
        }

        if (snext >= N) break;
        slot = snext;
        m0 = m1;
    }
}

// out[i,:64] = (xn[i]*nrm[i]) @ W2^T + b2   (f32 out)
// 512 threads, tile 128 nodes x 64 outs, thread = 4 nodes x 4 outs.
__global__ __launch_bounds__(512) void gemm2(const unsigned short* __restrict__ xn,
                                             const float* __restrict__ nrm,
                                             const float* __restrict__ W2,
                                             const float* __restrict__ b2,
                                             float* __restrict__ out,
                                             int N) {
    __shared__ __align__(16) float Wt[64 * 64];
    __shared__ __align__(16) float xT[64 * 128];
    const int tid  = threadIdx.x;
    const int tx   = tid & 15;
    const int ty   = tid >> 4;
    const int base = blockIdx.x * 128;

    {
        const float4* W4 = (const float4*)W2;
#pragma unroll
        for (int it = 0; it < 2; ++it) {
            int idx = tid + it * 512;
            int o = idx & 63, k4 = idx >> 6;
            float4 v = W4[o * 16 + k4];
            Wt[(4 * k4 + 0) * 64 + o] = v.x;
            Wt[(4 * k4 + 1) * 64 + o] = v.y;
            Wt[(4 * k4 + 2) * 64 + o] = v.z;
            Wt[(4 * k4 + 3) * 64 + o] = v.w;
        }
        const uint2* x2 = (const uint2*)xn;
#pragma unroll
        for (int it = 0; it < 4; ++it) {
            int idx = tid + it * 512;
            int mm = idx & 127, k4 = idx >> 7;
            int node = base + mm;
            U2H v; v.u = make_uint2(0u, 0u);
            float nn = 0.f;
            if (node < N) { v.u = x2[(size_t)node * 16 + k4]; nn = nrm[node]; }
            xT[(4 * k4 + 0) * 128 + mm] = (float)v.h[0].x * nn;
            xT[(4 * k4 + 1) * 128 + mm] = (float)v.h[0].y * nn;
            xT[(4 * k4 + 2) * 128 + mm] = (float)v.h[1].x * nn;
            xT[(4 * k4 + 3) * 128 + mm] = (float)v.h[1].y * nn;
        }
    }
    __syncthreads();

    float4 b4 = ((const float4*)b2)[tx];
    float4 acc[4];
    acc[0] = b4; acc[1] = b4; acc[2] = b4; acc[3] = b4;

#pragma unroll 4
    for (int k = 0; k < 64; ++k) {
        const float4 w4 = *(const float4*)&Wt[k * 64 + 4 * tx];
        const float4 xv = *(const float4*)&xT[k * 128 + 4 * ty];
        acc[0].x = fmaf(xv.x, w4.x, acc[0].x);
        acc[0].y = fmaf(xv.x, w4.y, acc[0].y);
        acc[0].z = fmaf(xv.x, w4.z, acc[0].z);
        acc[0].w = fmaf(xv.x, w4.w, acc[0].w);
        acc[1].x = fmaf(xv.y, w4.x, acc[1].x);
        acc[1].y = fmaf(xv.y, w4.y, acc[1].y);
        acc[1].z = fmaf(xv.y, w4.z, acc[1].z);
        acc[1].w = fmaf(xv.y, w4.w, acc[1].w);
        acc[2].x = fmaf(xv.z, w4.x, acc[2].x);
        acc[2].y = fmaf(xv.z, w4.y, acc[2].y);
        acc[2].z = fmaf(xv.z, w4.z, acc[2].z);
        acc[2].w = fmaf(xv.z, w4.w, acc[2].w);
        acc[3].x = fmaf(xv.w, w4.x, acc[3].x);
        acc[3].y = fmaf(xv.w, w4.y, acc[3].y);
        acc[3].z = fmaf(xv.w, w4.z, acc[3].z);
        acc[3].w = fmaf(xv.w, w4.w, acc[3].w);
    }

#pragma unroll
    for (int mm = 0; mm < 4; ++mm) {
        int node = base + 4 * ty + mm;
        if (node < N) *(float4*)&out[(size_t)node * 64 + 4 * tx] = acc[mm];
    }
}

extern "C" void kernel_launch(void* const* d_in, const int* in_sizes, int n_in,
                              void* d_out, int out_size, void* d_ws, size_t ws_size,
                              hipStream_t stream) {
    const float* x   = (const float*)d_in[0];
    const int*   row = (const int*)d_in[1];
    const int*   col = (const int*)d_in[2];
    const float* W1  = (const float*)d_in[3];
    const float* b1  = (const float*)d_in[4];
    const float* W2  = (const float*)d_in[5];
    const float* b2  = (const float*)d_in[6];
    float* out = (float*)d_out;

    const int N = in_sizes[0] / 128;
    const int E = in_sizes[1];

    char* ws = (char*)d_ws;
    size_t off = 0;
    unsigned short* ha = (unsigned short*)(ws + off); off += (size_t)N * 64 * 2;
    unsigned short* hb = (unsigned short*)(ws + off); off += (size_t)N * 64 * 2;
    float* na_  = (float*)(ws + off); off += (size_t)N * sizeof(float);
    float* nb_  = (float*)(ws + off); off += (size_t)N * sizeof(float);
    int*   ptr  = (int*)  (ws + off); off += (size_t)(N + 1) * sizeof(int);
    off = (off + 15) & ~(size_t)15;
    int4*  meta = (int4*) (ws + off); off += (size_t)N * sizeof(int4);
    (void)ws_size; (void)n_in; (void)out_size;

    build_rowptr_scan<<<(E + 255) / 256, 256, 0, stream>>>(row, ptr, N, E);

    build_perm_seg<<<(N + PSEG - 1) / PSEG, 1024, 0, stream>>>(ptr, meta, N);

    const int nbG = (N + 127) / 128;
    gemm1_relu<<<nbG, 512, 0, stream>>>(x, W1, b1, ha, na_, N);

    // persistent: 8 blocks/CU x 256 CUs
    int nbA = 2048;
    const int maxB = (N + 15) / 16;
    if (nbA > maxB) nbA = maxB;
    const int stride = nbA * 16;

    unsigned short* hc = ha; unsigned short* hn = hb;
    float* nc = na_; float* nn = nb_;
    for (int l = 0; l < 4; ++l) {
        agnn_layer<<<nbA, 256, 0, stream>>>((const uint4*)hc, nc, meta, col,
                                            (uint4*)hn, nn, N, stride);
        unsigned short* t = hc; hc = hn; hn = t;
        float* tf = nc; nc = nn; nn = tf;
    }

    gemm2<<<nbG, 512, 0, stream>>>(hc, nc, W2, b2, out, N);
}

// Round 7
// 296.653 us; speedup vs baseline: 1.1116x; 1.1116x over previous
//
#include <hip/hip_runtime.h>

// ---------------------------------------------------------------------------
// AGNN: h = relu(x@W1^T+b1); 4x [ h = relu(agnn(h)) ]; out = h@W2^T+b2
// N=100000, E=1600000, IN=128, HID=OUT=64, float32 in/out.
// Between layers: xn = h/(||h||+eps) stored FP16 (128 B/row) + nrm f32.
//   p = exp2( dot(xn_i * log2e, xn_j) );  out_i = sum p * nrm_j * xn_j / sum p
// Round 7: BURST-GATHER agnn.
//   r2-r6 model: per-wave MLP was ~2 row-loads in flight -> one ~600cy
//   latency exposure per edge-pair; more waves (r6) and 1-pair lookahead
//   (r3) both neutral/regressive. Fix: each 8-lane group loads its WHOLE
//   <=8-edge half (8 rows + 8 nrms, independent loads) in one burst, then
//   computes 8 bodies; latency exposed once per 8 edges. Masked clamp
//   handles tails; deg~16 -> usually 1 burst/node/group.
//   meta int4 (nid,p0,p1) from sort kills the perm->ptr->row chain.
//   Dynamic 6250-block launch (r6 static assignment regressed).
// gemm1/gemm2 (512 thr, prefetch), rowptr scan, 1024-seg sort kept.
// ---------------------------------------------------------------------------

typedef _Float16 h2 __attribute__((ext_vector_type(2)));

union U4H { uint4 u; h2 h[4]; };
union U2H { uint2 u; h2 h[2]; };
union UHI { unsigned u; h2 h; };
union UF  { unsigned u; float f; int i; };

#define DEV_INLINE __device__ __forceinline__

DEV_INLINE h2 mkh2(float a, float b) {
    h2 r; r.x = (_Float16)a; r.y = (_Float16)b; return r;
}

// x + dpp_perm(x): 0xB1 quad_perm xor1, 0x4E quad_perm xor2,
// 0x141 row_half_mirror (i^7), 0x140 row_mirror (i^15).
template <int CTRL>
DEV_INLINE float dpp_addf(float x) {
    UF a, b;
    a.f = x;
    b.i = __builtin_amdgcn_update_dpp(0, a.i, CTRL, 0xF, 0xF, true);
    return x + b.f;
}

// ptr[i] = lower_bound(row, i). Thread e covers i in (row[e-1], row[e]].
__global__ __launch_bounds__(256) void build_rowptr_scan(const int* __restrict__ row,
                                                         int* __restrict__ ptr,
                                                         int N, int E) {
    int e = blockIdx.x * blockDim.x + threadIdx.x;
    if (e >= E) return;
    const int r1 = row[e];
    const int r0 = (e == 0) ? -1 : row[e - 1];
    for (int i = r0 + 1; i <= r1; ++i) ptr[i] = e;
    if (e == E - 1) {
        for (int i = r1 + 1; i <= N; ++i) ptr[i] = E;
    }
}

// Segment-local counting sort by degree; emits meta[pos] = (nid, p0, p1, 0).
#define PSEG 1024
__global__ __launch_bounds__(1024) void build_perm_seg(const int* __restrict__ ptr,
                                                       int4* __restrict__ meta,
                                                       int N) {
    __shared__ int hist[256];
    __shared__ int tmp[256];
    const int t    = threadIdx.x;
    const int base = blockIdx.x * PSEG;
    const int end  = (base + PSEG < N) ? base + PSEG : N;
    const int cnt  = end - base;

    if (t < 256) hist[t] = 0;
    __syncthreads();

    int d = -1, p0v = 0, p1v = 0;
    if (t < cnt) {
        p0v = ptr[base + t];
        p1v = ptr[base + t + 1];
        d = p1v - p0v;
        if (d > 255) d = 255;
        atomicAdd(&hist[d], 1);
    }
    __syncthreads();

    int h0 = (t < 256) ? hist[t] : 0;
    int* src = hist; int* dst = tmp;
    for (int off = 1; off < 256; off <<= 1) {
        if (t < 256) dst[t] = src[t] + (t >= off ? src[t - off] : 0);
        __syncthreads();
        int* tt = src; src = dst; dst = tt;
    }
    if (t < 256) src[t] -= h0;
    __syncthreads();

    if (t < cnt) {
        int pos = base + atomicAdd(&src[d], 1);
        meta[pos] = make_int4(base + t, p0v, p1v, 0);
    }
}

// r = relu(x[i,:128]@W1^T + b1); xn[i]=f16(r/(||r||+eps)); nrm[i]=||r||+eps
// 512 threads, tile 128 nodes x 64 outs, thread = 4 nodes x 4 outs.
__global__ __launch_bounds__(512) void gemm1_relu(const float* __restrict__ x,
                                                  const float* __restrict__ W1,
                                                  const float* __restrict__ b1,
                                                  unsigned short* __restrict__ xn,
                                                  float* __restrict__ nrm,
                                                  int N) {
    __shared__ __align__(16) float Wt[32 * 64];    // 8 KiB
    __shared__ __align__(16) float xT[32 * 128];   // 16 KiB
    const int tid  = threadIdx.x;
    const int tx   = tid & 15;
    const int ty   = tid >> 4;
    const int base = blockIdx.x * 128;

    const float4* W4  = (const float4*)W1;
    const float4* x4p = (const float4*)x;

    const int wO  = tid & 63;
    const int wK4 = tid >> 6;
    const int mA  = tid & 127;
    const int kA  = tid >> 7;
    const int mB  = mA;
    const int kB  = kA + 4;
    const int nodeA = base + mA;

    float4 wv, xa_, xb_;
    wv = W4[wO * 32 + wK4];
    xa_ = make_float4(0.f, 0.f, 0.f, 0.f);
    xb_ = xa_;
    if (nodeA < N) {
        xa_ = x4p[(size_t)nodeA * 32 + kA];
        xb_ = x4p[(size_t)nodeA * 32 + kB];
    }

    float4 b4 = ((const float4*)b1)[tx];
    float4 acc[4];
    acc[0] = b4; acc[1] = b4; acc[2] = b4; acc[3] = b4;

    for (int c = 0; c < 4; ++c) {
        Wt[(4 * wK4 + 0) * 64 + wO] = wv.x;
        Wt[(4 * wK4 + 1) * 64 + wO] = wv.y;
        Wt[(4 * wK4 + 2) * 64 + wO] = wv.z;
        Wt[(4 * wK4 + 3) * 64 + wO] = wv.w;
        xT[(4 * kA + 0) * 128 + mA] = xa_.x;
        xT[(4 * kA + 1) * 128 + mA] = xa_.y;
        xT[(4 * kA + 2) * 128 + mA] = xa_.z;
        xT[(4 * kA + 3) * 128 + mA] = xa_.w;
        xT[(4 * kB + 0) * 128 + mB] = xb_.x;
        xT[(4 * kB + 1) * 128 + mB] = xb_.y;
        xT[(4 * kB + 2) * 128 + mB] = xb_.z;
        xT[(4 * kB + 3) * 128 + mB] = xb_.w;
        __syncthreads();

        if (c < 3) {
            const int ko = (c + 1) * 8;
            wv = W4[wO * 32 + ko + wK4];
            if (nodeA < N) {
                xa_ = x4p[(size_t)nodeA * 32 + ko + kA];
                xb_ = x4p[(size_t)nodeA * 32 + ko + kB];
            }
        }

#pragma unroll 4
        for (int k = 0; k < 32; ++k) {
            const float4 w4 = *(const float4*)&Wt[k * 64 + 4 * tx];
            const float4 xv = *(const float4*)&xT[k * 128 + 4 * ty];
            acc[0].x = fmaf(xv.x, w4.x, acc[0].x);
            acc[0].y = fmaf(xv.x, w4.y, acc[0].y);
            acc[0].z = fmaf(xv.x, w4.z, acc[0].z);
            acc[0].w = fmaf(xv.x, w4.w, acc[0].w);
            acc[1].x = fmaf(xv.y, w4.x, acc[1].x);
            acc[1].y = fmaf(xv.y, w4.y, acc[1].y);
            acc[1].z = fmaf(xv.y, w4.z, acc[1].z);
            acc[1].w = fmaf(xv.y, w4.w, acc[1].w);
            acc[2].x = fmaf(xv.z, w4.x, acc[2].x);
            acc[2].y = fmaf(xv.z, w4.y, acc[2].y);
            acc[2].z = fmaf(xv.z, w4.z, acc[2].z);
            acc[2].w = fmaf(xv.z, w4.w, acc[2].w);
            acc[3].x = fmaf(xv.w, w4.x, acc[3].x);
            acc[3].y = fmaf(xv.w, w4.y, acc[3].y);
            acc[3].z = fmaf(xv.w, w4.z, acc[3].z);
            acc[3].w = fmaf(xv.w, w4.w, acc[3].w);
        }
        if (c < 3) __syncthreads();
    }

#pragma unroll
    for (int mm = 0; mm < 4; ++mm) {
        float4 r = acc[mm];
        r.x = fmaxf(r.x, 0.f); r.y = fmaxf(r.y, 0.f);
        r.z = fmaxf(r.z, 0.f); r.w = fmaxf(r.w, 0.f);
        float s = fmaf(r.x, r.x, fmaf(r.y, r.y, fmaf(r.z, r.z, r.w * r.w)));
        s = dpp_addf<0xB1>(s);
        s = dpp_addf<0x4E>(s);
        s = dpp_addf<0x141>(s);
        s = dpp_addf<0x140>(s);
        const float nn  = sqrtf(s) + 1e-12f;
        const float inv = 1.f / nn;
        int node = base + 4 * ty + mm;
        if (node < N) {
            U2H pk;
            pk.h[0] = mkh2(r.x * inv, r.y * inv);
            pk.h[1] = mkh2(r.z * inv, r.w * inv);
            *(uint2*)&xn[(size_t)node * 64 + 4 * tx] = pk.u;
            if (tx == mm) nrm[node] = nn;
        }
    }
}

// BURST-GATHER agnn: 4 nodes/wave (16 lanes); 2 groups x 8 lanes take
// contiguous halves; per iteration a group loads 8 rows + 8 nrms as one
// burst of independent loads, then computes 8 masked edge bodies.
__global__ __launch_bounds__(256, 6) void agnn_layer(const uint4* __restrict__ xn4,
                                                     const float* __restrict__ nrm,
                                                     const int4* __restrict__ meta,
                                                     const int* __restrict__ col,
                                                     uint4* __restrict__ xo4,
                                                     float* __restrict__ nrmo,
                                                     int N) {
    const int tid  = threadIdx.x;
    const int lane = tid & 63;
    const int g    = (lane >> 3) & 1;   // edge group within 16-lane quarter
    const int sub  = lane & 7;          // 16B chunk of the 128B row
    const int slot = blockIdx.x * 16 + (tid >> 4);
    if (slot >= N) return;

    const int4 m0 = meta[slot];
    const int i  = m0.x;
    const int p0 = m0.y, p1 = m0.z;

    U4H hi_;
    hi_.u = xn4[(unsigned)i * 8u + sub];
    {
        const _Float16 L2E = (_Float16)1.4426950408889634f;
        h2 l2 = {L2E, L2E};
#pragma unroll
        for (int c = 0; c < 4; ++c) hi_.h[c] *= l2;   // p = exp2(dot)
    }

    const int mid = p0 + ((p1 - p0 + 1) >> 1);
    int       t   = g ? mid : p0;
    const int e_  = g ? p1  : mid;

    float den = 0.f;
    U4H acc;
    acc.h[0] = mkh2(0.f, 0.f); acc.h[1] = mkh2(0.f, 0.f);
    acc.h[2] = mkh2(0.f, 0.f); acc.h[3] = mkh2(0.f, 0.f);

    for (; t < e_; t += 8) {
        const int nb = e_ - t;              // >= 1
        int   jj[8];
        uint4 v[8];
        float nm[8];

        // index burst (contiguous, L1/L2-hit)
#pragma unroll
        for (int k = 0; k < 8; ++k) {
            int e = t + k;
            e = (e < e_) ? e : (e_ - 1);    // clamp tail (masked below)
            jj[k] = col[e];
        }
        // row + nrm burst: 16 independent loads in flight
#pragma unroll
        for (int k = 0; k < 8; ++k) v[k] = xn4[(unsigned)jj[k] * 8u + sub];
#pragma unroll
        for (int k = 0; k < 8; ++k) nm[k] = nrm[jj[k]];

        // 8 masked bodies
#pragma unroll
        for (int k = 0; k < 8; ++k) {
            U4H xa; xa.u = v[k];
            float sa = __builtin_amdgcn_fdot2(hi_.h[0], xa.h[0], 0.f, false);
            sa = __builtin_amdgcn_fdot2(hi_.h[1], xa.h[1], sa, false);
            float sb = __builtin_amdgcn_fdot2(hi_.h[2], xa.h[2], 0.f, false);
            sb = __builtin_amdgcn_fdot2(hi_.h[3], xa.h[3], sb, false);
            float s = sa + sb;
            s = dpp_addf<0xB1>(s);
            s = dpp_addf<0x4E>(s);
            s = dpp_addf<0x141>(s);
            const float p = (k < nb) ? exp2f(s) : 0.f;
            den += p;
            const _Float16 wh = (_Float16)(p * nm[k]);
            h2 w2 = {wh, wh};
            acc.h[0] += w2 * xa.h[0];
            acc.h[1] += w2 * xa.h[1];
            acc.h[2] += w2 * xa.h[2];
            acc.h[3] += w2 * xa.h[3];
        }
    }

    // merge groups: den group-uniform -> row_mirror; acc exact xor8
    den = dpp_addf<0x140>(den);
#pragma unroll
    for (int c = 0; c < 4; ++c) {
        UHI a; a.h = acc.h[c];
        UHI b; b.u = (unsigned)__shfl_xor((int)a.u, 8, 64);
        acc.h[c] = a.h + b.h;
    }

    const float id = 1.f / fmaxf(den, 1e-12f);
    float o[8];
#pragma unroll
    for (int c = 0; c < 4; ++c) {
        o[2 * c]     = fmaxf((float)acc.h[c].x * id, 0.f);
        o[2 * c + 1] = fmaxf((float)acc.h[c].y * id, 0.f);
    }

    float s2 = 0.f;
#pragma unroll
    for (int c = 0; c < 8; ++c) s2 = fmaf(o[c], o[c], s2);
    s2 = dpp_addf<0xB1>(s2);
    s2 = dpp_addf<0x4E>(s2);
    s2 = dpp_addf<0x141>(s2);
    const float nn  = sqrtf(s2) + 1e-12f;
    const float inv = 1.f / nn;

    if (g == 0) {
        U4H ov;
        ov.h[0] = mkh2(o[0] * inv, o[1] * inv);
        ov.h[1] = mkh2(o[2] * inv, o[3] * inv);
        ov.h[2] = mkh2(o[4] * inv, o[5] * inv);
        ov.h[3] = mkh2(o[6] * inv, o[7] * inv);
        xo4[(unsigned)i * 8u + sub] = ov.u;
        if (sub == 0) nrmo[i] = nn;
    }
}

// out[i,:64] = (xn[i]*nrm[i]) @ W2^T + b2   (f32 out)
// 512 threads, tile 128 nodes x 64 outs, thread = 4 nodes x 4 outs.
__global__ __launch_bounds__(512) void gemm2(const unsigned short* __restrict__ xn,
                                             const float* __restrict__ nrm,
                                             const float* __restrict__ W2,
                                             const float* __restrict__ b2,
                                             float* __restrict__ out,
                                             int N) {
    __shared__ __align__(16) float Wt[64 * 64];
    __shared__ __align__(16) float xT[64 * 128];
    const int tid  = threadIdx.x;
    const int tx   = tid & 15;
    const int ty   = tid >> 4;
    const int base = blockIdx.x * 128;

    {
        const float4* W4 = (const float4*)W2;
#pragma unroll
        for (int it = 0; it < 2; ++it) {
            int idx = tid + it * 512;
            int o = idx & 63, k4 = idx >> 6;
            float4 v = W4[o * 16 + k4];
            Wt[(4 * k4 + 0) * 64 + o] = v.x;
            Wt[(4 * k4 + 1) * 64 + o] = v.y;
            Wt[(4 * k4 + 2) * 64 + o] = v.z;
            Wt[(4 * k4 + 3) * 64 + o] = v.w;
        }
        const uint2* x2 = (const uint2*)xn;
#pragma unroll
        for (int it = 0; it < 4; ++it) {
            int idx = tid + it * 512;
            int mm = idx & 127, k4 = idx >> 7;
            int node = base + mm;
            U2H v; v.u = make_uint2(0u, 0u);
            float nn = 0.f;
            if (node < N) { v.u = x2[(size_t)node * 16 + k4]; nn = nrm[node]; }
            xT[(4 * k4 + 0) * 128 + mm] = (float)v.h[0].x * nn;
            xT[(4 * k4 + 1) * 128 + mm] = (float)v.h[0].y * nn;
            xT[(4 * k4 + 2) * 128 + mm] = (float)v.h[1].x * nn;
            xT[(4 * k4 + 3) * 128 + mm] = (float)v.h[1].y * nn;
        }
    }
    __syncthreads();

    float4 b4 = ((const float4*)b2)[tx];
    float4 acc[4];
    acc[0] = b4; acc[1] = b4; acc[2] = b4; acc[3] = b4;

#pragma unroll 4
    for (int k = 0; k < 64; ++k) {
        const float4 w4 = *(const float4*)&Wt[k * 64 + 4 * tx];
        const float4 xv = *(const float4*)&xT[k * 128 + 4 * ty];
        acc[0].x = fmaf(xv.x, w4.x, acc[0].x);
        acc[0].y = fmaf(xv.x, w4.y, acc[0].y);
        acc[0].z = fmaf(xv.x, w4.z, acc[0].z);
        acc[0].w = fmaf(xv.x, w4.w, acc[0].w);
        acc[1].x = fmaf(xv.y, w4.x, acc[1].x);
        acc[1].y = fmaf(xv.y, w4.y, acc[1].y);
        acc[1].z = fmaf(xv.y, w4.z, acc[1].z);
        acc[1].w = fmaf(xv.y, w4.w, acc[1].w);
        acc[2].x = fmaf(xv.z, w4.x, acc[2].x);
        acc[2].y = fmaf(xv.z, w4.y, acc[2].y);
        acc[2].z = fmaf(xv.z, w4.z, acc[2].z);
        acc[2].w = fmaf(xv.z, w4.w, acc[2].w);
        acc[3].x = fmaf(xv.w, w4.x, acc[3].x);
        acc[3].y = fmaf(xv.w, w4.y, acc[3].y);
        acc[3].z = fmaf(xv.w, w4.z, acc[3].z);
        acc[3].w = fmaf(xv.w, w4.w, acc[3].w);
    }

#pragma unroll
    for (int mm = 0; mm < 4; ++mm) {
        int node = base + 4 * ty + mm;
        if (node < N) *(float4*)&out[(size_t)node * 64 + 4 * tx] = acc[mm];
    }
}

extern "C" void kernel_launch(void* const* d_in, const int* in_sizes, int n_in,
                              void* d_out, int out_size, void* d_ws, size_t ws_size,
                              hipStream_t stream) {
    const float* x   = (const float*)d_in[0];
    const int*   row = (const int*)d_in[1];
    const int*   col = (const int*)d_in[2];
    const float* W1  = (const float*)d_in[3];
    const float* b1  = (const float*)d_in[4];
    const float* W2  = (const float*)d_in[5];
    const float* b2  = (const float*)d_in[6];
    float* out = (float*)d_out;

    const int N = in_sizes[0] / 128;
    const int E = in_sizes[1];

    char* ws = (char*)d_ws;
    size_t off = 0;
    unsigned short* ha = (unsigned short*)(ws + off); off += (size_t)N * 64 * 2;
    unsigned short* hb = (unsigned short*)(ws + off); off += (size_t)N * 64 * 2;
    float* na_  = (float*)(ws + off); off += (size_t)N * sizeof(float);
    float* nb_  = (float*)(ws + off); off += (size_t)N * sizeof(float);
    int*   ptr  = (int*)  (ws + off); off += (size_t)(N + 1) * sizeof(int);
    off = (off + 15) & ~(size_t)15;
    int4*  meta = (int4*) (ws + off); off += (size_t)N * sizeof(int4);
    (void)ws_size; (void)n_in; (void)out_size;

    build_rowptr_scan<<<(E + 255) / 256, 256, 0, stream>>>(row, ptr, N, E);

    build_perm_seg<<<(N + PSEG - 1) / PSEG, 1024, 0, stream>>>(ptr, meta, N);

    const int nbG = (N + 127) / 128;
    gemm1_relu<<<nbG, 512, 0, stream>>>(x, W1, b1, ha, na_, N);

    const int nb16 = (N + 15) / 16;
    unsigned short* hc = ha; unsigned short* hn = hb;
    float* nc = na_; float* nn = nb_;
    for (int l = 0; l < 4; ++l) {
        agnn_layer<<<nb16, 256, 0, stream>>>((const uint4*)hc, nc, meta, col,
                                             (uint4*)hn, nn, N);
        unsigned short* t = hc; hc = hn; hn = t;
        float* tf = nc; nc = nn; nn = tf;
    }

    gemm2<<<nbG, 512, 0, stream>>>(hc, nc, W2, b2, out, N);
}